// Round 7
// baseline (578.864 us; speedup 1.0000x reference)
//
#include <hip/hip_runtime.h>
#include <hip/hip_bf16.h>

// MoE: B=4,S=4096,D=512,E=16,H=2048,top-2. T=16384 tokens, 32768 slots.
#define T_TOK 16384
#define DDIM  512
#define NEXP  16
#define HDIM  2048
#define NSLOT (T_TOK * 2)
#define NHB   128         // histogram blocks: NSLOT / 256

#define GBM 128           // m-tile (tile table granularity)
#define MAXTILE 272       // max m-tiles: 32768/128 + 16

// fused-kernel LDS byte offsets
#define LP0  1024         // P buffer: 128 rows x 272 B (pad) = 34816
#define LSG  35840        // staging region: 3 bufs x 32 KB = 98304; total 134144

typedef __attribute__((ext_vector_type(8))) short short8;   // 8 x bf16
typedef __attribute__((ext_vector_type(4))) short short4v;
typedef __attribute__((ext_vector_type(4))) float f32x4;

__device__ inline short f2bf(float f) {
    __hip_bfloat16 h = __float2bfloat16(f);
    return *reinterpret_cast<short*>(&h);
}
__device__ inline float geluf(float v) {   // exact gelu
    return 0.5f * v * (1.0f + erff(v * 0.70710678118654752440f));
}
// async global->LDS, 16B per lane. LDS dest = WAVE-UNIFORM base + lane*16.
__device__ inline void gload16(const void* g, void* l) {
    __builtin_amdgcn_global_load_lds(
        (const __attribute__((address_space(1))) void*)g,
        (__attribute__((address_space(3))) void*)l, 16, 0, 0);
}

// ---------------- routing ----------------
// wave-per-token gate: lane (g,q) = (d-quarter, expert). fp64 (tie-robust).
__global__ __launch_bounds__(256) void gate_kernel(
    const float* __restrict__ x, const float* __restrict__ wg,
    const float* __restrict__ bg, int* __restrict__ tok_e,
    float* __restrict__ tok_w)
{
    int wv = threadIdx.x >> 6, lane = threadIdx.x & 63;
    int t = blockIdx.x * 4 + wv;
    int g = lane >> 4, q = lane & 15;
    const float* xr = x + (size_t)t * DDIM + g * 128;
    const float* wr = wg + (size_t)g * 128 * NEXP + q;
    double a0 = 0, a1 = 0, a2 = 0, a3 = 0;
#pragma unroll
    for (int c = 0; c < 8; ++c) {
        float4 v0 = ((const float4*)xr)[c * 4 + 0];
        float4 v1 = ((const float4*)xr)[c * 4 + 1];
        float4 v2 = ((const float4*)xr)[c * 4 + 2];
        float4 v3 = ((const float4*)xr)[c * 4 + 3];
        const float* wp = wr + c * 16 * NEXP;
        a0 += (double)v0.x * (double)wp[0 * NEXP];
        a1 += (double)v0.y * (double)wp[1 * NEXP];
        a2 += (double)v0.z * (double)wp[2 * NEXP];
        a3 += (double)v0.w * (double)wp[3 * NEXP];
        a0 += (double)v1.x * (double)wp[4 * NEXP];
        a1 += (double)v1.y * (double)wp[5 * NEXP];
        a2 += (double)v1.z * (double)wp[6 * NEXP];
        a3 += (double)v1.w * (double)wp[7 * NEXP];
        a0 += (double)v2.x * (double)wp[8 * NEXP];
        a1 += (double)v2.y * (double)wp[9 * NEXP];
        a2 += (double)v2.z * (double)wp[10 * NEXP];
        a3 += (double)v2.w * (double)wp[11 * NEXP];
        a0 += (double)v3.x * (double)wp[12 * NEXP];
        a1 += (double)v3.y * (double)wp[13 * NEXP];
        a2 += (double)v3.z * (double)wp[14 * NEXP];
        a3 += (double)v3.w * (double)wp[15 * NEXP];
    }
    double a = ((a0 + a1) + (a2 + a3));
    a += __shfl_xor(a, 16, 64);
    a += __shfl_xor(a, 32, 64);
    a += (double)bg[q];
    double v0 = a; int i0 = q;
#pragma unroll
    for (int s = 1; s < 16; s <<= 1) {
        double ov = __shfl_xor(v0, s, 64);
        int oi = __shfl_xor(i0, s, 64);
        if (ov > v0 || (ov == v0 && oi < i0)) { v0 = ov; i0 = oi; }
    }
    double m2 = (q == i0) ? -1e300 : a;
    double v1 = m2; int i1 = q;
#pragma unroll
    for (int s = 1; s < 16; s <<= 1) {
        double ov = __shfl_xor(v1, s, 64);
        int oi = __shfl_xor(i1, s, 64);
        if (ov > v1 || (ov == v1 && oi < i1)) { v1 = ov; i1 = oi; }
    }
    if (lane == 0) {
        float ex = expf((float)(v1 - v0));      // <= 1
        float w0 = 1.0f / (1.0f + ex);
        tok_e[2 * t] = i0; tok_e[2 * t + 1] = i1;
        tok_w[2 * t] = w0; tok_w[2 * t + 1] = ex * w0;
    }
}

// per-block expert histogram (LDS atomics only)
__global__ __launch_bounds__(256) void hist_kernel(
    const int* __restrict__ tok_e, int* __restrict__ bhist)
{
    __shared__ int h[NEXP];
    if (threadIdx.x < NEXP) h[threadIdx.x] = 0;
    __syncthreads();
    atomicAdd(&h[tok_e[blockIdx.x * 256 + threadIdx.x]], 1);
    __syncthreads();
    if (threadIdx.x < NEXP) bhist[blockIdx.x * NEXP + threadIdx.x] = h[threadIdx.x];
}

// offs[0..16] = exclusive scan; offs[17] = ntiles; bbase[b][e] = scatter base.
__global__ void scan_kernel(const int* __restrict__ bhist, int* __restrict__ offs,
                            int* __restrict__ bbase, int* __restrict__ tile_e,
                            int* __restrict__ tile_m0)
{
    int tid = threadIdx.x;
    __shared__ int tot[NEXP];
    if (tid < NEXP) {
        int s = 0;
        for (int b = 0; b < NHB; ++b) s += bhist[b * NEXP + tid];
        tot[tid] = s;
    }
    __syncthreads();
    if (tid == 0) {
        int run = 0;
        for (int e = 0; e < NEXP; ++e) { offs[e] = run; run += tot[e]; }
        offs[NEXP] = run;   // == NSLOT
        int nt = 0;
        for (int e = 0; e < NEXP; ++e)
            for (int m = offs[e]; m < offs[e + 1]; m += GBM) {
                tile_e[nt] = e; tile_m0[nt] = m; ++nt;
            }
        offs[17] = nt;
    }
    __syncthreads();
    if (tid < NEXP) {
        int run = offs[tid];
        for (int b = 0; b < NHB; ++b) {
            bbase[b * NEXP + tid] = run;
            run += bhist[b * NEXP + tid];
        }
    }
}

// local rank via LDS atomic + precomputed block base
__global__ __launch_bounds__(256) void scatter_kernel(
    const int* __restrict__ tok_e, const float* __restrict__ tok_w,
    const int* __restrict__ bbase, int* __restrict__ list_tok,
    float* __restrict__ list_w, int* __restrict__ pos_tk)
{
    __shared__ int h[NEXP];
    if (threadIdx.x < NEXP) h[threadIdx.x] = 0;
    __syncthreads();
    int s = blockIdx.x * 256 + threadIdx.x;
    int e = tok_e[s];
    int r = atomicAdd(&h[e], 1);
    int pos = bbase[blockIdx.x * NEXP + e] + r;
    list_tok[pos] = s >> 1;
    list_w[pos] = tok_w[s];
    pos_tk[s] = pos;
}

// ---------------- pre-conversion ----------------

__global__ void cvt_bf16_kernel(const float* __restrict__ src, short* __restrict__ dst, int n4)
{
    int i = blockIdx.x * blockDim.x + threadIdx.x;
    int stride = gridDim.x * blockDim.x;
    for (; i < n4; i += stride) {
        float4 v = ((const float4*)src)[i];
        short4v o;
        o[0] = f2bf(v.x); o[1] = f2bf(v.y); o[2] = f2bf(v.z); o[3] = f2bf(v.w);
        ((short4v*)dst)[i] = o;
    }
}

// transpose one [R][C] fp32 matrix per blockIdx.z into [C][R] bf16
__global__ void wtrans_kernel(const float* __restrict__ src, short* __restrict__ dst, int R, int C)
{
    __shared__ float t[32][33];
    int c0 = blockIdx.x * 32, r0 = blockIdx.y * 32;
    const float* s = src + (size_t)blockIdx.z * R * C;
    short* d = dst + (size_t)blockIdx.z * R * C;
    int cc = threadIdx.x & 31, rr = threadIdx.x >> 5;
#pragma unroll
    for (int pp = 0; pp < 4; ++pp)
        t[rr + pp * 8][cc] = s[(size_t)(r0 + rr + pp * 8) * C + c0 + cc];
    __syncthreads();
#pragma unroll
    for (int pp = 0; pp < 4; ++pp) {
        int c = rr + pp * 8;
        d[(size_t)(c0 + c) * R + r0 + cc] = f2bf(t[cc][c]);
    }
}

// ---------------- fused expert FFN ----------------
// One block per 128-slot m-tile; 512 threads = 8 waves (2M x 4N).
// Loop 16 h-chunks of 128:
//   phase 1: P(128x128) = gelu(X(128x512) @ W1chunk^T), K=512, BK=64, 8 steps,
//            3-buf counted-vmcnt(4) pipeline; P -> LDS (272 B row pad).
//   phase 2: y(128x512) += P @ W2chunk^T, K=128, BK=32, 4 steps, 3-buf
//            counted-vmcnt(4); A-frags from P_lds, y accumulates in VGPRs.
// Eliminates the 268 MB hbuf HBM round-trip that limited the split kernels.

__global__ __launch_bounds__(512, 2) void ffn_kernel(
    const short* __restrict__ xbf, const short* __restrict__ w1t,
    const short* __restrict__ w2t, const float* __restrict__ b1,
    const float* __restrict__ b2, const int* __restrict__ offs,
    const int* __restrict__ tile_e, const int* __restrict__ tile_m0,
    const int* __restrict__ list_tok, const float* __restrict__ list_w,
    float* __restrict__ ybuf, float* __restrict__ out, int mode)
{
    __shared__ __align__(16) char smem[134144];
    if ((int)blockIdx.x >= offs[17]) return;
    int e = tile_e[blockIdx.x], m0 = tile_m0[blockIdx.x];
    int rows = offs[e + 1] - m0; if (rows > GBM) rows = GBM;
    int tid = threadIdx.x, l = tid & 63, w = tid >> 6;
    int l15 = l & 15, kq = l >> 4;
    int wm = w >> 2, wn = w & 3;

    int* ts = (int*)smem;
    float* lw = (float*)(smem + 512);
    if (tid < GBM) {
        int idx = m0 + (tid < rows ? tid : rows - 1);
        ts[tid] = list_tok[idx];
        lw[tid] = list_w[idx];
    }
    __syncthreads();

    // phase-1 staging sources (BK=64: 2 instr for A, 2 for B1 per wave)
    // instr i: row = w*16 + i*8 + (l>>3), phys 16B-slot l&7,
    // source fetches LOGICAL slot (l&7)^((row>>1)&7)  [both-sides swizzle]
    int p1r0 = w * 16 + (l >> 3);
    int p1r1 = p1r0 + 8;
    int sA0 = (l & 7) ^ ((p1r0 >> 1) & 7);
    int sA1 = (l & 7) ^ ((p1r1 >> 1) & 7);
    const short* gA0 = xbf + (size_t)ts[p1r0] * DDIM + sA0 * 8;
    const short* gA1 = xbf + (size_t)ts[p1r1] * DDIM + sA1 * 8;
    const short* w1e = w1t + (size_t)e * HDIM * DDIM;
    const short* gB0 = w1e + (size_t)p1r0 * DDIM + sA0 * 8;
    const short* gB1 = w1e + (size_t)p1r1 * DDIM + sA1 * 8;

    // phase-2 staging sources (BK=32: 4 instr per wave; d-rows w*64..+64)
    const short* gW0; const short* gW1; const short* gW2; const short* gW3;
    {
        int d0 = w * 64 + 0 * 16 + (l >> 2);
        int d1 = w * 64 + 1 * 16 + (l >> 2);
        int d2 = w * 64 + 2 * 16 + (l >> 2);
        int d3 = w * 64 + 3 * 16 + (l >> 2);
        gW0 = w2t + ((size_t)e * DDIM + d0) * HDIM + (((l & 3) ^ ((d0 >> 1) & 3)) * 8);
        gW1 = w2t + ((size_t)e * DDIM + d1) * HDIM + (((l & 3) ^ ((d1 >> 1) & 3)) * 8);
        gW2 = w2t + ((size_t)e * DDIM + d2) * HDIM + (((l & 3) ^ ((d2 >> 1) & 3)) * 8);
        gW3 = w2t + ((size_t)e * DDIM + d3) * HDIM + (((l & 3) ^ ((d3 >> 1) & 3)) * 8);
    }

    // fragment row indices / offsets
    int aR[4], paof[4];
#pragma unroll
    for (int mi = 0; mi < 4; ++mi) {
        int R = wm * 64 + mi * 16 + l15;
        aR[mi] = R;
        paof[mi] = LP0 + R * 272 + kq * 16;
    }
    int bS1[2];
#pragma unroll
    for (int ni = 0; ni < 2; ++ni) bS1[ni] = wn * 32 + ni * 16 + l15;
    int pbof[8];
#pragma unroll
    for (int ni = 0; ni < 8; ++ni) {
        int S = wn * 128 + ni * 16 + l15;
        pbof[ni] = S * 64 + ((kq ^ ((S >> 1) & 3)) * 16);
    }

    f32x4 vzero = {0.0f, 0.0f, 0.0f, 0.0f};
    f32x4 acc2[4][8];
#pragma unroll
    for (int mi = 0; mi < 4; ++mi)
#pragma unroll
        for (int ni = 0; ni < 8; ++ni) acc2[mi][ni] = vzero;

#pragma unroll 1
    for (int hb = 0; hb < 16; ++hb) {
        // ---------- phase 1 ----------
        f32x4 acc1[4][2];
#pragma unroll
        for (int mi = 0; mi < 4; ++mi)
#pragma unroll
            for (int ni = 0; ni < 2; ++ni) acc1[mi][ni] = vzero;
        const short* hB0 = gB0 + (size_t)hb * 128 * DDIM;
        const short* hB1 = gB1 + (size_t)hb * 128 * DDIM;

#define STG1(T, B) {                                             \
        char* d = smem + LSG + (B) * 32768 + w * 2048;           \
        gload16(gA0 + (T) * 64, d);                              \
        gload16(gA1 + (T) * 64, d + 1024);                       \
        gload16(hB0 + (T) * 64, d + 16384);                      \
        gload16(hB1 + (T) * 64, d + 16384 + 1024); }

        STG1(0, 0);
        STG1(1, 1);
        int cb = 0, sb = 2;
#pragma unroll 1
        for (int t = 0; t < 8; ++t) {
            if (t < 7) asm volatile("s_waitcnt vmcnt(4)" ::: "memory");
            else       asm volatile("s_waitcnt vmcnt(0)" ::: "memory");
            __builtin_amdgcn_s_barrier();
            __builtin_amdgcn_sched_barrier(0);
            if (t + 2 < 8) STG1(t + 2, sb);
            const char* Ab = smem + LSG + cb * 32768;
            const char* Bb = Ab + 16384;
#pragma unroll
            for (int ks = 0; ks < 2; ++ks) {
                short8 af[4], bv[2];
#pragma unroll
                for (int mi = 0; mi < 4; ++mi)
                    af[mi] = *(const short8*)(Ab + aR[mi] * 128 +
                        (((ks * 4 + kq) ^ ((aR[mi] >> 1) & 7)) * 16));
#pragma unroll
                for (int ni = 0; ni < 2; ++ni)
                    bv[ni] = *(const short8*)(Bb + bS1[ni] * 128 +
                        (((ks * 4 + kq) ^ ((bS1[ni] >> 1) & 7)) * 16));
                __builtin_amdgcn_s_setprio(1);
#pragma unroll
                for (int mi = 0; mi < 4; ++mi)
#pragma unroll
                    for (int ni = 0; ni < 2; ++ni)
                        acc1[mi][ni] = __builtin_amdgcn_mfma_f32_16x16x32_bf16(
                            af[mi], bv[ni], acc1[mi][ni], 0, 0, 0);
                __builtin_amdgcn_s_setprio(0);
            }
            cb = (cb == 2) ? 0 : cb + 1;
            sb = (sb == 2) ? 0 : sb + 1;
        }
#undef STG1

        // bias + gelu + P -> LDS (row pad 272 B keeps phase-2 reads ~2-way)
        float bias1[2];
#pragma unroll
        for (int ni = 0; ni < 2; ++ni)
            bias1[ni] = b1[e * HDIM + hb * 128 + bS1[ni]];
#pragma unroll
        for (int mi = 0; mi < 4; ++mi)
#pragma unroll
            for (int ni = 0; ni < 2; ++ni)
#pragma unroll
                for (int j = 0; j < 4; ++j) {
                    int row = wm * 64 + mi * 16 + kq * 4 + j;
                    float v = acc1[mi][ni][j] + bias1[ni];
                    *(short*)(smem + LP0 + row * 272 + bS1[ni] * 2) = f2bf(geluf(v));
                }
        __syncthreads();

        // ---------- phase 2 ----------
#define STG2(T, B) {                                             \
        char* d = smem + LSG + (B) * 32768 + w * 4096;           \
        gload16(gW0 + hb * 128 + (T) * 32, d);                   \
        gload16(gW1 + hb * 128 + (T) * 32, d + 1024);            \
        gload16(gW2 + hb * 128 + (T) * 32, d + 2048);            \
        gload16(gW3 + hb * 128 + (T) * 32, d + 3072); }

        STG2(0, 0);
        STG2(1, 1);
        int c2 = 0, s2 = 2;
#pragma unroll 1
        for (int t = 0; t < 4; ++t) {
            if (t < 3) asm volatile("s_waitcnt vmcnt(4)" ::: "memory");
            else       asm volatile("s_waitcnt vmcnt(0)" ::: "memory");
            __builtin_amdgcn_s_barrier();
            __builtin_amdgcn_sched_barrier(0);
            if (t + 2 < 4) STG2(t + 2, s2);
            const char* Bb = smem + LSG + c2 * 32768;
            short8 pa[4], bv[8];
#pragma unroll
            for (int mi = 0; mi < 4; ++mi)
                pa[mi] = *(const short8*)(smem + paof[mi] + t * 64);
#pragma unroll
            for (int ni = 0; ni < 8; ++ni)
                bv[ni] = *(const short8*)(Bb + pbof[ni]);
            __builtin_amdgcn_s_setprio(1);
#pragma unroll
            for (int mi = 0; mi < 4; ++mi)
#pragma unroll
                for (int ni = 0; ni < 8; ++ni)
                    acc2[mi][ni] = __builtin_amdgcn_mfma_f32_16x16x32_bf16(
                        pa[mi], bv[ni], acc2[mi][ni], 0, 0, 0);
            __builtin_amdgcn_s_setprio(0);
            c2 = (c2 == 2) ? 0 : c2 + 1;
            s2 = (s2 == 2) ? 0 : s2 + 1;
        }
#undef STG2
        __syncthreads();   // staging bufs reused by next hb's phase 1
    }

    // epilogue: +b2 once (full K accumulated), write y per slot
#pragma unroll
    for (int mi = 0; mi < 4; ++mi)
#pragma unroll
        for (int ni = 0; ni < 8; ++ni) {
            int col = wn * 128 + ni * 16 + l15;
            float bias = b2[e * DDIM + col];
#pragma unroll
            for (int j = 0; j < 4; ++j) {
                int row = wm * 64 + mi * 16 + kq * 4 + j;
                if (row < rows) {
                    float v = acc2[mi][ni][j] + bias;
                    if (mode == 0)
                        ybuf[(size_t)(m0 + row) * DDIM + col] = v;
                    else
                        atomicAdd(&out[(size_t)ts[row] * DDIM + col], lw[row] * v);
                }
            }
        }
}

// out[t] = w0*ybuf[pos0] + w1*ybuf[pos1]
__global__ __launch_bounds__(256) void combine_kernel(
    const float* __restrict__ ybuf, const int* __restrict__ pos_tk,
    const float* __restrict__ tok_w, float* __restrict__ out)
{
    int i = blockIdx.x * 256 + threadIdx.x;   // over T_TOK * 128 float4 units
    int t = i >> 7, c = i & 127;
    float w0 = tok_w[2 * t], w1 = tok_w[2 * t + 1];
    int p0 = pos_tk[2 * t], p1 = pos_tk[2 * t + 1];
    float4 a = ((const float4*)ybuf)[(size_t)p0 * 128 + c];
    float4 b = ((const float4*)ybuf)[(size_t)p1 * 128 + c];
    float4 o;
    o.x = w0 * a.x + w1 * b.x;
    o.y = w0 * a.y + w1 * b.y;
    o.z = w0 * a.z + w1 * b.z;
    o.w = w0 * a.w + w1 * b.w;
    ((float4*)out)[(size_t)t * 128 + c] = o;
}

// ---------------- launch ----------------

extern "C" void kernel_launch(void* const* d_in, const int* in_sizes, int n_in,
                              void* d_out, int out_size, void* d_ws, size_t ws_size,
                              hipStream_t stream)
{
    const float* x  = (const float*)d_in[0];
    const float* wg = (const float*)d_in[1];
    const float* bg = (const float*)d_in[2];
    const float* w1 = (const float*)d_in[3];
    const float* b1 = (const float*)d_in[4];
    const float* w2 = (const float*)d_in[5];
    const float* b2 = (const float*)d_in[6];
    float* out = (float*)d_out;

    char* p = (char*)d_ws;
    int* offs     = (int*)(p + 128);            // 32 ints
    int* tile_e   = (int*)(p + 256);            // 512 ints
    int* tile_m0  = (int*)(p + 2304);           // 512 ints
    int* bhist    = (int*)(p + 8192);           // 8 KiB
    int* bbase    = (int*)(p + 16384);          // 8 KiB
    int* tok_e    = (int*)(p + 32768);          // 128 KiB
    float* tok_w  = (float*)(p + 32768 + 131072);
    int* list_tok = (int*)(p + 32768 + 262144);
    float* list_w = (float*)(p + 32768 + 393216);
    int* pos_tk   = (int*)(p + 32768 + 524288);
    short* xbf    = (short*)(p + 32768 + 655360);             // 16 MiB
    short* w1t    = xbf + (size_t)T_TOK * DDIM;               // 32 MiB
    short* w2t    = w1t + (size_t)NEXP * DDIM * HDIM;         // 32 MiB
    char* after   = (char*)(w2t + (size_t)NEXP * DDIM * HDIM);
    size_t fixed  = (size_t)(after - p);

    // mode 0: per-slot fp32 ybuf + combine (no atomics). mode 1: atomic out.
    int mode = (fixed + (size_t)NSLOT * DDIM * 4 <= ws_size) ? 0 : 1;
    float* ybuf = (float*)after;

    if (mode == 1) hipMemsetAsync(d_out, 0, (size_t)out_size * sizeof(float), stream);

    gate_kernel<<<T_TOK / 4, 256, 0, stream>>>(x, wg, bg, tok_e, tok_w);
    hist_kernel<<<NHB, 256, 0, stream>>>(tok_e, bhist);
    scan_kernel<<<1, 64, 0, stream>>>(bhist, offs, bbase, tile_e, tile_m0);
    scatter_kernel<<<NHB, 256, 0, stream>>>(tok_e, tok_w, bbase, list_tok, list_w, pos_tk);
    cvt_bf16_kernel<<<2048, 256, 0, stream>>>(x, xbf, T_TOK * DDIM / 4);
    wtrans_kernel<<<dim3(HDIM / 32, DDIM / 32, NEXP), 256, 0, stream>>>(w1, w1t, DDIM, HDIM);
    wtrans_kernel<<<dim3(DDIM / 32, HDIM / 32, NEXP), 256, 0, stream>>>(w2, w2t, HDIM, DDIM);

    ffn_kernel<<<MAXTILE, 512, 0, stream>>>(
        xbf, w1t, w2t, b1, b2, offs, tile_e, tile_m0, list_tok, list_w,
        ybuf, out, mode);

    if (mode == 0)
        combine_kernel<<<T_TOK * 128 / 256, 256, 0, stream>>>(ybuf, pos_tk, tok_w, out);
}

// Round 8
// 455.947 us; speedup vs baseline: 1.2696x; 1.2696x over previous
//
#include <hip/hip_runtime.h>
#include <hip/hip_bf16.h>

// MoE: B=4,S=4096,D=512,E=16,H=2048,top-2. T=16384 tokens, 32768 slots.
#define T_TOK 16384
#define DDIM  512
#define NEXP  16
#define HDIM  2048
#define NSLOT (T_TOK * 2)
#define NHB   128         // histogram blocks: NSLOT / 256

#define GBM 128           // gemm tile M (matches tile table)
#define GBN 256           // gemm tile N
#define BK  32            // gemm K-step
#define MAXTILE 272       // max m-tiles: 32768/128 + 16
#define TSLICE  136       // m-tile slice: hbuf slice ~71 MB stays L3-resident

typedef __attribute__((ext_vector_type(8))) short short8;   // 8 x bf16
typedef __attribute__((ext_vector_type(4))) short short4v;
typedef __attribute__((ext_vector_type(4))) float f32x4;

__device__ inline short f2bf(float f) {
    __hip_bfloat16 h = __float2bfloat16(f);
    return *reinterpret_cast<short*>(&h);
}
__device__ inline float bf2f(short s) {
    unsigned u = ((unsigned)(unsigned short)s) << 16;
    union { unsigned u; float f; } c; c.u = u; return c.f;
}
__device__ inline float geluf(float v) {   // exact gelu
    return 0.5f * v * (1.0f + erff(v * 0.70710678118654752440f));
}
// async global->LDS, 16B per lane. LDS dest = WAVE-UNIFORM base + lane*16.
__device__ inline void gload16(const void* g, void* l) {
    __builtin_amdgcn_global_load_lds(
        (const __attribute__((address_space(1))) void*)g,
        (__attribute__((address_space(3))) void*)l, 16, 0, 0);
}

// ---------------- routing ----------------
// wave-per-token gate: lane (g,q) = (d-quarter, expert). fp64 (tie-robust).
__global__ __launch_bounds__(256) void gate_kernel(
    const float* __restrict__ x, const float* __restrict__ wg,
    const float* __restrict__ bg, int* __restrict__ tok_e,
    float* __restrict__ tok_w)
{
    int wv = threadIdx.x >> 6, lane = threadIdx.x & 63;
    int t = blockIdx.x * 4 + wv;
    int g = lane >> 4, q = lane & 15;
    const float* xr = x + (size_t)t * DDIM + g * 128;
    const float* wr = wg + (size_t)g * 128 * NEXP + q;
    double a0 = 0, a1 = 0, a2 = 0, a3 = 0;
#pragma unroll
    for (int c = 0; c < 8; ++c) {
        float4 v0 = ((const float4*)xr)[c * 4 + 0];
        float4 v1 = ((const float4*)xr)[c * 4 + 1];
        float4 v2 = ((const float4*)xr)[c * 4 + 2];
        float4 v3 = ((const float4*)xr)[c * 4 + 3];
        const float* wp = wr + c * 16 * NEXP;
        a0 += (double)v0.x * (double)wp[0 * NEXP];
        a1 += (double)v0.y * (double)wp[1 * NEXP];
        a2 += (double)v0.z * (double)wp[2 * NEXP];
        a3 += (double)v0.w * (double)wp[3 * NEXP];
        a0 += (double)v1.x * (double)wp[4 * NEXP];
        a1 += (double)v1.y * (double)wp[5 * NEXP];
        a2 += (double)v1.z * (double)wp[6 * NEXP];
        a3 += (double)v1.w * (double)wp[7 * NEXP];
        a0 += (double)v2.x * (double)wp[8 * NEXP];
        a1 += (double)v2.y * (double)wp[9 * NEXP];
        a2 += (double)v2.z * (double)wp[10 * NEXP];
        a3 += (double)v2.w * (double)wp[11 * NEXP];
        a0 += (double)v3.x * (double)wp[12 * NEXP];
        a1 += (double)v3.y * (double)wp[13 * NEXP];
        a2 += (double)v3.z * (double)wp[14 * NEXP];
        a3 += (double)v3.w * (double)wp[15 * NEXP];
    }
    double a = ((a0 + a1) + (a2 + a3));
    a += __shfl_xor(a, 16, 64);
    a += __shfl_xor(a, 32, 64);
    a += (double)bg[q];
    double v0 = a; int i0 = q;
#pragma unroll
    for (int s = 1; s < 16; s <<= 1) {
        double ov = __shfl_xor(v0, s, 64);
        int oi = __shfl_xor(i0, s, 64);
        if (ov > v0 || (ov == v0 && oi < i0)) { v0 = ov; i0 = oi; }
    }
    double m2 = (q == i0) ? -1e300 : a;
    double v1 = m2; int i1 = q;
#pragma unroll
    for (int s = 1; s < 16; s <<= 1) {
        double ov = __shfl_xor(v1, s, 64);
        int oi = __shfl_xor(i1, s, 64);
        if (ov > v1 || (ov == v1 && oi < i1)) { v1 = ov; i1 = oi; }
    }
    if (lane == 0) {
        float ex = expf((float)(v1 - v0));      // <= 1
        float w0 = 1.0f / (1.0f + ex);
        tok_e[2 * t] = i0; tok_e[2 * t + 1] = i1;
        tok_w[2 * t] = w0; tok_w[2 * t + 1] = ex * w0;
    }
}

// per-block expert histogram (LDS atomics only)
__global__ __launch_bounds__(256) void hist_kernel(
    const int* __restrict__ tok_e, int* __restrict__ bhist)
{
    __shared__ int h[NEXP];
    if (threadIdx.x < NEXP) h[threadIdx.x] = 0;
    __syncthreads();
    atomicAdd(&h[tok_e[blockIdx.x * 256 + threadIdx.x]], 1);
    __syncthreads();
    if (threadIdx.x < NEXP) bhist[blockIdx.x * NEXP + threadIdx.x] = h[threadIdx.x];
}

// offs[0..16] = exclusive scan; offs[17] = ntiles; bbase[b][e] = scatter base.
__global__ void scan_kernel(const int* __restrict__ bhist, int* __restrict__ offs,
                            int* __restrict__ bbase, int* __restrict__ tile_e,
                            int* __restrict__ tile_m0)
{
    int tid = threadIdx.x;
    __shared__ int tot[NEXP];
    if (tid < NEXP) {
        int s = 0;
        for (int b = 0; b < NHB; ++b) s += bhist[b * NEXP + tid];
        tot[tid] = s;
    }
    __syncthreads();
    if (tid == 0) {
        int run = 0;
        for (int e = 0; e < NEXP; ++e) { offs[e] = run; run += tot[e]; }
        offs[NEXP] = run;   // == NSLOT
        int nt = 0;
        for (int e = 0; e < NEXP; ++e)
            for (int m = offs[e]; m < offs[e + 1]; m += GBM) {
                tile_e[nt] = e; tile_m0[nt] = m; ++nt;
            }
        offs[17] = nt;
    }
    __syncthreads();
    if (tid < NEXP) {
        int run = offs[tid];
        for (int b = 0; b < NHB; ++b) {
            bbase[b * NEXP + tid] = run;
            run += bhist[b * NEXP + tid];
        }
    }
}

// local rank via LDS atomic + precomputed block base
__global__ __launch_bounds__(256) void scatter_kernel(
    const int* __restrict__ tok_e, const float* __restrict__ tok_w,
    const int* __restrict__ bbase, int* __restrict__ list_tok,
    float* __restrict__ list_w, int* __restrict__ pos_tk)
{
    __shared__ int h[NEXP];
    if (threadIdx.x < NEXP) h[threadIdx.x] = 0;
    __syncthreads();
    int s = blockIdx.x * 256 + threadIdx.x;
    int e = tok_e[s];
    int r = atomicAdd(&h[e], 1);
    int pos = bbase[blockIdx.x * NEXP + e] + r;
    list_tok[pos] = s >> 1;
    list_w[pos] = tok_w[s];
    pos_tk[s] = pos;
}

// ---------------- pre-conversion ----------------

__global__ void cvt_bf16_kernel(const float* __restrict__ src, short* __restrict__ dst, int n4)
{
    int i = blockIdx.x * blockDim.x + threadIdx.x;
    int stride = gridDim.x * blockDim.x;
    for (; i < n4; i += stride) {
        float4 v = ((const float4*)src)[i];
        short4v o;
        o[0] = f2bf(v.x); o[1] = f2bf(v.y); o[2] = f2bf(v.z); o[3] = f2bf(v.w);
        ((short4v*)dst)[i] = o;
    }
}

// transpose one [R][C] fp32 matrix per blockIdx.z into [C][R] bf16
__global__ void wtrans_kernel(const float* __restrict__ src, short* __restrict__ dst, int R, int C)
{
    __shared__ float t[32][33];
    int c0 = blockIdx.x * 32, r0 = blockIdx.y * 32;
    const float* s = src + (size_t)blockIdx.z * R * C;
    short* d = dst + (size_t)blockIdx.z * R * C;
    int cc = threadIdx.x & 31, rr = threadIdx.x >> 5;
#pragma unroll
    for (int pp = 0; pp < 4; ++pp)
        t[rr + pp * 8][cc] = s[(size_t)(r0 + rr + pp * 8) * C + c0 + cc];
    __syncthreads();
#pragma unroll
    for (int pp = 0; pp < 4; ++pp) {
        int c = rr + pp * 8;
        d[(size_t)(c0 + c) * R + r0 + cc] = f2bf(t[cc][c]);
    }
}

// ---------------- expert GEMMs: counted-vmcnt 3-buffer pipeline ----------------
// 128x256 tile, BK=32, 512 threads = 8 waves (2M x 4N), 64x64 per wave.
// LDS: 3 bufs x (A 8KB + B 16KB) = 72 KB -> 2 blocks/CU.
// Per K-step: vmcnt(3) counted -> raw s_barrier -> sched_barrier(0) ->
// stage(t+2) -> 8 ds_read_b128 -> setprio-wrapped 16 MFMA. One barrier/step.
// T2 swizzle both-sides (pre-swizzled gather source + swizzled read).
// Round-7 lesson: mega-fusion (1 blk/CU) loses to this split (TLP + L3 share).

#define PRO_FRAG_OFFS(aoff, boff)                                        \
    int l15 = l & 15, kq = l >> 4;                                       \
    int aoff[4], boff[4];                                                \
    _Pragma("unroll")                                                    \
    for (int mi = 0; mi < 4; ++mi) {                                     \
        int R = (w >> 2) * 64 + mi * 16 + l15;                           \
        aoff[mi] = R * BK + ((kq ^ ((R >> 1) & 3)) * 8);                 \
    }                                                                    \
    _Pragma("unroll")                                                    \
    for (int ni = 0; ni < 4; ++ni) {                                     \
        int S = (w & 3) * 64 + ni * 16 + l15;                            \
        boff[ni] = S * BK + ((kq ^ ((S >> 1) & 3)) * 8);                 \
    }

__global__ __launch_bounds__(512) void gemm1_kernel(
    const short* __restrict__ xbf, const short* __restrict__ w1t,
    const float* __restrict__ b1, const int* __restrict__ offs,
    const int* __restrict__ tile_e, const int* __restrict__ tile_m0,
    const int* __restrict__ list_tok, short* __restrict__ hbuf,
    int h0, int hlen, int t0)
{
    int tb = t0 + (int)blockIdx.x;
    if (tb >= offs[17]) return;
    int e = tile_e[tb], m0 = tile_m0[tb];
    int rows = offs[e + 1] - m0; if (rows > GBM) rows = GBM;
    int n0 = blockIdx.y * GBN;
    int tid = threadIdx.x, l = tid & 63, w = tid >> 6;

    __shared__ __align__(16) short As[3][GBM * BK];   // 3 x 8 KiB
    __shared__ __align__(16) short Bs[3][GBN * BK];   // 3 x 16 KiB
    __shared__ int ts[GBM];
    if (tid < GBM) ts[tid] = list_tok[m0 + (tid < rows ? tid : rows - 1)];
    __syncthreads();

    int arow = w * 16 + (l >> 2);
    int aslot = (l & 3) ^ ((arow >> 1) & 3);
    const short* gA = xbf + (size_t)ts[arow] * DDIM + aslot * 8;
    int brow0 = (w * 2 + 0) * 16 + (l >> 2);
    int brow1 = (w * 2 + 1) * 16 + (l >> 2);
    int bs0 = (l & 3) ^ ((brow0 >> 1) & 3);
    int bs1 = (l & 3) ^ ((brow1 >> 1) & 3);
    const short* gB0 = w1t + ((size_t)e * HDIM + (size_t)(h0 + n0 + brow0)) * DDIM + bs0 * 8;
    const short* gB1 = w1t + ((size_t)e * HDIM + (size_t)(h0 + n0 + brow1)) * DDIM + bs1 * 8;

    PRO_FRAG_OFFS(aoff, boff)

    f32x4 vzero = {0.0f, 0.0f, 0.0f, 0.0f};
    f32x4 acc[4][4];
#pragma unroll
    for (int i = 0; i < 4; ++i)
#pragma unroll
        for (int j = 0; j < 4; ++j) acc[i][j] = vzero;

#define STAGE1(T, B) {                                            \
        gload16(gA  + (T) * BK, &As[B][w * 512]);                 \
        gload16(gB0 + (T) * BK, &Bs[B][(w * 2 + 0) * 512]);       \
        gload16(gB1 + (T) * BK, &Bs[B][(w * 2 + 1) * 512]); }

    const int nt = DDIM / BK;          // 16
    STAGE1(0, 0);
    STAGE1(1, 1);
    int cb = 0, sb = 2;
#pragma unroll 1
    for (int t = 0; t < nt; ++t) {
        if (t < nt - 1) asm volatile("s_waitcnt vmcnt(3)" ::: "memory");
        else            asm volatile("s_waitcnt vmcnt(0)" ::: "memory");
        __builtin_amdgcn_s_barrier();
        __builtin_amdgcn_sched_barrier(0);
        if (t + 2 < nt) STAGE1(t + 2, sb);
        const short* Ab = &As[cb][0];
        const short* Bb = &Bs[cb][0];
        short8 af[4], bv[4];
#pragma unroll
        for (int mi = 0; mi < 4; ++mi) af[mi] = *(const short8*)(Ab + aoff[mi]);
#pragma unroll
        for (int ni = 0; ni < 4; ++ni) bv[ni] = *(const short8*)(Bb + boff[ni]);
        __builtin_amdgcn_s_setprio(1);
#pragma unroll
        for (int mi = 0; mi < 4; ++mi)
#pragma unroll
            for (int ni = 0; ni < 4; ++ni)
                acc[mi][ni] = __builtin_amdgcn_mfma_f32_16x16x32_bf16(
                    af[mi], bv[ni], acc[mi][ni], 0, 0, 0);
        __builtin_amdgcn_s_setprio(0);
        cb = (cb == 2) ? 0 : cb + 1;
        sb = (sb == 2) ? 0 : sb + 1;
    }
#undef STAGE1

    int crow = (w >> 2) * 64 + ((l >> 4) << 2);
    int ccol = (w & 3) * 64 + (l & 15);
#pragma unroll
    for (int mi = 0; mi < 4; ++mi) {
#pragma unroll
        for (int ni = 0; ni < 4; ++ni) {
            int col = ccol + ni * 16;
            float bias = b1[e * HDIM + h0 + n0 + col];
#pragma unroll
            for (int j = 0; j < 4; ++j) {
                int row = crow + mi * 16 + j;
                if (row < rows) {
                    float v = acc[mi][ni][j] + bias;
                    hbuf[(size_t)(m0 + row) * hlen + (n0 + col)] = f2bf(geluf(v));
                }
            }
        }
    }
}

__global__ __launch_bounds__(512) void gemm2_kernel(
    const short* __restrict__ hbuf, const short* __restrict__ w2t,
    const float* __restrict__ b2, const int* __restrict__ offs,
    const int* __restrict__ tile_e, const int* __restrict__ tile_m0,
    const int* __restrict__ list_tok, const float* __restrict__ list_w,
    short* __restrict__ ybuf, float* __restrict__ out,
    int h0, int hlen, int mode, int t0)
{
    int tb = t0 + (int)blockIdx.x;
    if (tb >= offs[17]) return;
    int e = tile_e[tb], m0 = tile_m0[tb];
    int rows = offs[e + 1] - m0; if (rows > GBM) rows = GBM;
    int n0 = blockIdx.y * GBN;            // output d coordinate
    int tid = threadIdx.x, l = tid & 63, w = tid >> 6;

    __shared__ __align__(16) short As[3][GBM * BK];
    __shared__ __align__(16) short Bs[3][GBN * BK];
    __shared__ int ts[GBM];
    __shared__ float lw[GBM];
    if (tid < GBM) {
        int idx = m0 + (tid < rows ? tid : rows - 1);
        ts[tid] = list_tok[idx];
        lw[tid] = list_w[idx];
    }
    __syncthreads();

    int arow = w * 16 + (l >> 2);
    int aslot = (l & 3) ^ ((arow >> 1) & 3);
    int aslotg = m0 + arow; if (aslotg >= NSLOT) aslotg = NSLOT - 1;
    const short* gA = hbuf + (size_t)aslotg * hlen + aslot * 8;
    int brow0 = (w * 2 + 0) * 16 + (l >> 2);
    int brow1 = (w * 2 + 1) * 16 + (l >> 2);
    int bs0 = (l & 3) ^ ((brow0 >> 1) & 3);
    int bs1 = (l & 3) ^ ((brow1 >> 1) & 3);
    const short* gB0 = w2t + ((size_t)e * DDIM + (size_t)(n0 + brow0)) * HDIM + h0 + bs0 * 8;
    const short* gB1 = w2t + ((size_t)e * DDIM + (size_t)(n0 + brow1)) * HDIM + h0 + bs1 * 8;

    PRO_FRAG_OFFS(aoff, boff)

    f32x4 vzero = {0.0f, 0.0f, 0.0f, 0.0f};
    f32x4 acc[4][4];
#pragma unroll
    for (int i = 0; i < 4; ++i)
#pragma unroll
        for (int j = 0; j < 4; ++j) acc[i][j] = vzero;

#define STAGE2(T, B) {                                            \
        gload16(gA  + (T) * BK, &As[B][w * 512]);                 \
        gload16(gB0 + (T) * BK, &Bs[B][(w * 2 + 0) * 512]);       \
        gload16(gB1 + (T) * BK, &Bs[B][(w * 2 + 1) * 512]); }

    const int nt = hlen / BK;          // 64 at hlen=2048
    STAGE2(0, 0);
    STAGE2(1, 1);
    int cb = 0, sb = 2;
#pragma unroll 1
    for (int t = 0; t < nt; ++t) {
        if (t < nt - 1) asm volatile("s_waitcnt vmcnt(3)" ::: "memory");
        else            asm volatile("s_waitcnt vmcnt(0)" ::: "memory");
        __builtin_amdgcn_s_barrier();
        __builtin_amdgcn_sched_barrier(0);
        if (t + 2 < nt) STAGE2(t + 2, sb);
        const short* Ab = &As[cb][0];
        const short* Bb = &Bs[cb][0];
        short8 af[4], bv[4];
#pragma unroll
        for (int mi = 0; mi < 4; ++mi) af[mi] = *(const short8*)(Ab + aoff[mi]);
#pragma unroll
        for (int ni = 0; ni < 4; ++ni) bv[ni] = *(const short8*)(Bb + boff[ni]);
        __builtin_amdgcn_s_setprio(1);
#pragma unroll
        for (int mi = 0; mi < 4; ++mi)
#pragma unroll
            for (int ni = 0; ni < 4; ++ni)
                acc[mi][ni] = __builtin_amdgcn_mfma_f32_16x16x32_bf16(
                    af[mi], bv[ni], acc[mi][ni], 0, 0, 0);
        __builtin_amdgcn_s_setprio(0);
        cb = (cb == 2) ? 0 : cb + 1;
        sb = (sb == 2) ? 0 : sb + 1;
    }
#undef STAGE2

    int crow = (w >> 2) * 64 + ((l >> 4) << 2);
    int ccol = (w & 3) * 64 + (l & 15);
#pragma unroll
    for (int mi = 0; mi < 4; ++mi) {
#pragma unroll
        for (int ni = 0; ni < 4; ++ni) {
            int col = ccol + ni * 16;
            float bias = (h0 == 0) ? b2[e * DDIM + n0 + col] : 0.0f;
#pragma unroll
            for (int j = 0; j < 4; ++j) {
                int row = crow + mi * 16 + j;
                if (row < rows) {
                    float v = acc[mi][ni][j] + bias;
                    if (mode == 0)   // full-K path: single bf16 write
                        ybuf[(size_t)(m0 + row) * DDIM + n0 + col] = f2bf(v);
                    else
                        atomicAdd(&out[(size_t)ts[row] * DDIM + n0 + col], lw[row] * v);
                }
            }
        }
    }
}

// out[t] = w0*ybuf[pos0] + w1*ybuf[pos1]  (ybuf bf16, 8 cols/thread)
__global__ __launch_bounds__(256) void combine_kernel(
    const short* __restrict__ ybuf, const int* __restrict__ pos_tk,
    const float* __restrict__ tok_w, float* __restrict__ out)
{
    int i = blockIdx.x * 256 + threadIdx.x;   // over T_TOK * 64 units
    int t = i >> 6, c = (i & 63) * 8;
    float w0 = tok_w[2 * t], w1 = tok_w[2 * t + 1];
    int p0 = pos_tk[2 * t], p1 = pos_tk[2 * t + 1];
    short8 a = *(const short8*)(ybuf + (size_t)p0 * DDIM + c);
    short8 b = *(const short8*)(ybuf + (size_t)p1 * DDIM + c);
    float4 o0, o1;
    float* op = (float*)&o0;
#pragma unroll
    for (int j = 0; j < 4; ++j) op[j] = w0 * bf2f(a[j]) + w1 * bf2f(b[j]);
    float* op1 = (float*)&o1;
#pragma unroll
    for (int j = 0; j < 4; ++j) op1[j] = w0 * bf2f(a[4 + j]) + w1 * bf2f(b[4 + j]);
    float4* ob = (float4*)(out + (size_t)t * DDIM + c);
    ob[0] = o0;
    ob[1] = o1;
}

// ---------------- launch ----------------

extern "C" void kernel_launch(void* const* d_in, const int* in_sizes, int n_in,
                              void* d_out, int out_size, void* d_ws, size_t ws_size,
                              hipStream_t stream)
{
    const float* x  = (const float*)d_in[0];
    const float* wg = (const float*)d_in[1];
    const float* bg = (const float*)d_in[2];
    const float* w1 = (const float*)d_in[3];
    const float* b1 = (const float*)d_in[4];
    const float* w2 = (const float*)d_in[5];
    const float* b2 = (const float*)d_in[6];
    float* out = (float*)d_out;

    char* p = (char*)d_ws;
    int* offs     = (int*)(p + 128);            // 32 ints
    int* tile_e   = (int*)(p + 256);            // 512 ints
    int* tile_m0  = (int*)(p + 2304);           // 512 ints
    int* bhist    = (int*)(p + 8192);           // 8 KiB
    int* bbase    = (int*)(p + 16384);          // 8 KiB
    int* tok_e    = (int*)(p + 32768);          // 128 KiB
    float* tok_w  = (float*)(p + 32768 + 131072);
    int* list_tok = (int*)(p + 32768 + 262144);
    float* list_w = (float*)(p + 32768 + 393216);
    int* pos_tk   = (int*)(p + 32768 + 524288);
    short* xbf    = (short*)(p + 32768 + 655360);             // 16 MiB
    short* w1t    = xbf + (size_t)T_TOK * DDIM;               // 32 MiB
    short* w2t    = w1t + (size_t)NEXP * DDIM * HDIM;         // 32 MiB
    char* after   = (char*)(w2t + (size_t)NEXP * DDIM * HDIM);
    size_t fixed  = (size_t)(after - p);

    // mode 0: full-K gemm2 + bf16 ybuf + combine (needs hbuf 134 MB + ybuf 33.5 MB)
    // mode 1 fallback: h-chunked gemm2 with atomic out accumulate.
    int mode, hlen = HDIM;
    if (fixed + (size_t)NSLOT * DDIM * 2 + (size_t)NSLOT * HDIM * 2 <= ws_size) {
        mode = 0;
    } else {
        mode = 1;
        hlen = 0;
        for (int hl = HDIM; hl >= 128; hl >>= 1)
            if (fixed + (size_t)NSLOT * hl * 2 <= ws_size) { hlen = hl; break; }
    }
    short* ybuf = (short*)after;
    short* hbuf = (mode == 0) ? (short*)(after + (size_t)NSLOT * DDIM * 2) : (short*)after;

    if (!hlen) { hipMemsetAsync(d_out, 0, (size_t)out_size * sizeof(float), stream); return; }
    if (mode == 1) hipMemsetAsync(d_out, 0, (size_t)out_size * sizeof(float), stream);

    gate_kernel<<<T_TOK / 4, 256, 0, stream>>>(x, wg, bg, tok_e, tok_w);
    hist_kernel<<<NHB, 256, 0, stream>>>(tok_e, bhist);
    scan_kernel<<<1, 64, 0, stream>>>(bhist, offs, bbase, tile_e, tile_m0);
    scatter_kernel<<<NHB, 256, 0, stream>>>(tok_e, tok_w, bbase, list_tok, list_w, pos_tk);
    cvt_bf16_kernel<<<2048, 256, 0, stream>>>(x, xbf, T_TOK * DDIM / 4);
    wtrans_kernel<<<dim3(HDIM / 32, DDIM / 32, NEXP), 256, 0, stream>>>(w1, w1t, DDIM, HDIM);
    wtrans_kernel<<<dim3(DDIM / 32, HDIM / 32, NEXP), 256, 0, stream>>>(w2, w2t, HDIM, DDIM);

    // m-tile slices: gemm2(slice) consumes hbuf(slice) while it is L3-hot.
    for (int h0 = 0; h0 < HDIM; h0 += hlen) {
        for (int t0 = 0; t0 < MAXTILE; t0 += TSLICE) {
            int tc = MAXTILE - t0; if (tc > TSLICE) tc = TSLICE;
            gemm1_kernel<<<dim3(tc, hlen / GBN), 512, 0, stream>>>(
                xbf, w1t, b1, offs, tile_e, tile_m0, list_tok, hbuf, h0, hlen, t0);
            gemm2_kernel<<<dim3(tc, DDIM / GBN), 512, 0, stream>>>(
                hbuf, w2t, b2, offs, tile_e, tile_m0, list_tok, list_w,
                ybuf, out, h0, hlen, mode, t0);
        }
    }
    if (mode == 0)
        combine_kernel<<<T_TOK * 64 / 256, 256, 0, stream>>>(ybuf, pos_tk, tok_w, out);
}

// Round 9
// 425.233 us; speedup vs baseline: 1.3613x; 1.0722x over previous
//
#include <hip/hip_runtime.h>
#include <hip/hip_bf16.h>

// MoE: B=4,S=4096,D=512,E=16,H=2048,top-2. T=16384 tokens, 32768 slots.
#define T_TOK 16384
#define DDIM  512
#define NEXP  16
#define HDIM  2048
#define NSLOT (T_TOK * 2)
#define NHB   128         // histogram blocks: NSLOT / 256

#define GBM 128           // gemm tile M (matches tile table)
#define GBN 256           // gemm1 tile N
#define GBN2 128          // gemm2 tile N (3 blk/CU + 544 blocks/slice)
#define BK  32            // gemm K-step
#define MAXTILE 272       // max m-tiles: 32768/128 + 16
#define TSLICE  136       // m-tile slice: hbuf slice ~71 MB stays L3-resident

typedef __attribute__((ext_vector_type(8))) short short8;   // 8 x bf16
typedef __attribute__((ext_vector_type(4))) short short4v;
typedef __attribute__((ext_vector_type(4))) float f32x4;

__device__ inline short f2bf(float f) {
    __hip_bfloat16 h = __float2bfloat16(f);
    return *reinterpret_cast<short*>(&h);
}
__device__ inline float bf2f(short s) {
    unsigned u = ((unsigned)(unsigned short)s) << 16;
    union { unsigned u; float f; } c; c.u = u; return c.f;
}
// A&S 7.1.26 erf: |abs err| < 1.5e-7 (<< bf16 rounding of hbuf). ~14 VALU ops.
__device__ inline float erf_fast(float x) {
    float ax = fabsf(x);
    float t = 1.0f / fmaf(0.3275911f, ax, 1.0f);
    float p = fmaf(fmaf(fmaf(fmaf(1.061405429f, t, -1.453152027f), t,
                  1.421413741f), t, -0.284496736f), t, 0.254829592f) * t;
    float r = 1.0f - p * __expf(-ax * ax);
    return copysignf(r, x);
}
__device__ inline float geluf(float v) {   // exact-form gelu via fast erf
    return 0.5f * v * (1.0f + erf_fast(v * 0.70710678118654752440f));
}
// async global->LDS, 16B per lane. LDS dest = WAVE-UNIFORM base + lane*16.
__device__ inline void gload16(const void* g, void* l) {
    __builtin_amdgcn_global_load_lds(
        (const __attribute__((address_space(1))) void*)g,
        (__attribute__((address_space(3))) void*)l, 16, 0, 0);
}

// ---------------- routing ----------------
// wave-per-token gate: lane (g,q) = (d-quarter, expert). fp64 (tie-robust).
__global__ __launch_bounds__(256) void gate_kernel(
    const float* __restrict__ x, const float* __restrict__ wg,
    const float* __restrict__ bg, int* __restrict__ tok_e,
    float* __restrict__ tok_w)
{
    int wv = threadIdx.x >> 6, lane = threadIdx.x & 63;
    int t = blockIdx.x * 4 + wv;
    int g = lane >> 4, q = lane & 15;
    const float* xr = x + (size_t)t * DDIM + g * 128;
    const float* wr = wg + (size_t)g * 128 * NEXP + q;
    double a0 = 0, a1 = 0, a2 = 0, a3 = 0;
#pragma unroll
    for (int c = 0; c < 8; ++c) {
        float4 v0 = ((const float4*)xr)[c * 4 + 0];
        float4 v1 = ((const float4*)xr)[c * 4 + 1];
        float4 v2 = ((const float4*)xr)[c * 4 + 2];
        float4 v3 = ((const float4*)xr)[c * 4 + 3];
        const float* wp = wr + c * 16 * NEXP;
        a0 += (double)v0.x * (double)wp[0 * NEXP];
        a1 += (double)v0.y * (double)wp[1 * NEXP];
        a2 += (double)v0.z * (double)wp[2 * NEXP];
        a3 += (double)v0.w * (double)wp[3 * NEXP];
        a0 += (double)v1.x * (double)wp[4 * NEXP];
        a1 += (double)v1.y * (double)wp[5 * NEXP];
        a2 += (double)v1.z * (double)wp[6 * NEXP];
        a3 += (double)v1.w * (double)wp[7 * NEXP];
        a0 += (double)v2.x * (double)wp[8 * NEXP];
        a1 += (double)v2.y * (double)wp[9 * NEXP];
        a2 += (double)v2.z * (double)wp[10 * NEXP];
        a3 += (double)v2.w * (double)wp[11 * NEXP];
        a0 += (double)v3.x * (double)wp[12 * NEXP];
        a1 += (double)v3.y * (double)wp[13 * NEXP];
        a2 += (double)v3.z * (double)wp[14 * NEXP];
        a3 += (double)v3.w * (double)wp[15 * NEXP];
    }
    double a = ((a0 + a1) + (a2 + a3));
    a += __shfl_xor(a, 16, 64);
    a += __shfl_xor(a, 32, 64);
    a += (double)bg[q];
    double v0 = a; int i0 = q;
#pragma unroll
    for (int s = 1; s < 16; s <<= 1) {
        double ov = __shfl_xor(v0, s, 64);
        int oi = __shfl_xor(i0, s, 64);
        if (ov > v0 || (ov == v0 && oi < i0)) { v0 = ov; i0 = oi; }
    }
    double m2 = (q == i0) ? -1e300 : a;
    double v1 = m2; int i1 = q;
#pragma unroll
    for (int s = 1; s < 16; s <<= 1) {
        double ov = __shfl_xor(v1, s, 64);
        int oi = __shfl_xor(i1, s, 64);
        if (ov > v1 || (ov == v1 && oi < i1)) { v1 = ov; i1 = oi; }
    }
    if (lane == 0) {
        float ex = expf((float)(v1 - v0));      // <= 1
        float w0 = 1.0f / (1.0f + ex);
        tok_e[2 * t] = i0; tok_e[2 * t + 1] = i1;
        tok_w[2 * t] = w0; tok_w[2 * t + 1] = ex * w0;
    }
}

// per-block expert histogram (LDS atomics only)
__global__ __launch_bounds__(256) void hist_kernel(
    const int* __restrict__ tok_e, int* __restrict__ bhist)
{
    __shared__ int h[NEXP];
    if (threadIdx.x < NEXP) h[threadIdx.x] = 0;
    __syncthreads();
    atomicAdd(&h[tok_e[blockIdx.x * 256 + threadIdx.x]], 1);
    __syncthreads();
    if (threadIdx.x < NEXP) bhist[blockIdx.x * NEXP + threadIdx.x] = h[threadIdx.x];
}

// offs[0..16] = exclusive scan; offs[17] = ntiles; bbase[b][e] = scatter base.
__global__ void scan_kernel(const int* __restrict__ bhist, int* __restrict__ offs,
                            int* __restrict__ bbase, int* __restrict__ tile_e,
                            int* __restrict__ tile_m0)
{
    int tid = threadIdx.x;
    __shared__ int tot[NEXP];
    if (tid < NEXP) {
        int s = 0;
        for (int b = 0; b < NHB; ++b) s += bhist[b * NEXP + tid];
        tot[tid] = s;
    }
    __syncthreads();
    if (tid == 0) {
        int run = 0;
        for (int e = 0; e < NEXP; ++e) { offs[e] = run; run += tot[e]; }
        offs[NEXP] = run;   // == NSLOT
        int nt = 0;
        for (int e = 0; e < NEXP; ++e)
            for (int m = offs[e]; m < offs[e + 1]; m += GBM) {
                tile_e[nt] = e; tile_m0[nt] = m; ++nt;
            }
        offs[17] = nt;
    }
    __syncthreads();
    if (tid < NEXP) {
        int run = offs[tid];
        for (int b = 0; b < NHB; ++b) {
            bbase[b * NEXP + tid] = run;
            run += bhist[b * NEXP + tid];
        }
    }
}

// local rank via LDS atomic + precomputed block base
__global__ __launch_bounds__(256) void scatter_kernel(
    const int* __restrict__ tok_e, const float* __restrict__ tok_w,
    const int* __restrict__ bbase, int* __restrict__ list_tok,
    float* __restrict__ list_w, int* __restrict__ pos_tk)
{
    __shared__ int h[NEXP];
    if (threadIdx.x < NEXP) h[threadIdx.x] = 0;
    __syncthreads();
    int s = blockIdx.x * 256 + threadIdx.x;
    int e = tok_e[s];
    int r = atomicAdd(&h[e], 1);
    int pos = bbase[blockIdx.x * NEXP + e] + r;
    list_tok[pos] = s >> 1;
    list_w[pos] = tok_w[s];
    pos_tk[s] = pos;
}

// ---------------- pre-conversion ----------------

__global__ void cvt_bf16_kernel(const float* __restrict__ src, short* __restrict__ dst, int n4)
{
    int i = blockIdx.x * blockDim.x + threadIdx.x;
    int stride = gridDim.x * blockDim.x;
    for (; i < n4; i += stride) {
        float4 v = ((const float4*)src)[i];
        short4v o;
        o[0] = f2bf(v.x); o[1] = f2bf(v.y); o[2] = f2bf(v.z); o[3] = f2bf(v.w);
        ((short4v*)dst)[i] = o;
    }
}

// transpose one [R][C] fp32 matrix per blockIdx.z into [C][R] bf16
__global__ void wtrans_kernel(const float* __restrict__ src, short* __restrict__ dst, int R, int C)
{
    __shared__ float t[32][33];
    int c0 = blockIdx.x * 32, r0 = blockIdx.y * 32;
    const float* s = src + (size_t)blockIdx.z * R * C;
    short* d = dst + (size_t)blockIdx.z * R * C;
    int cc = threadIdx.x & 31, rr = threadIdx.x >> 5;
#pragma unroll
    for (int pp = 0; pp < 4; ++pp)
        t[rr + pp * 8][cc] = s[(size_t)(r0 + rr + pp * 8) * C + c0 + cc];
    __syncthreads();
#pragma unroll
    for (int pp = 0; pp < 4; ++pp) {
        int c = rr + pp * 8;
        d[(size_t)(c0 + c) * R + r0 + cc] = f2bf(t[cc][c]);
    }
}

// ---------------- expert GEMMs: counted-vmcnt 3-buffer pipeline ----------------
// Per K-step: counted vmcnt -> raw s_barrier -> sched_barrier(0) ->
// stage(t+2) -> ds_read_b128 frags -> setprio-wrapped MFMA. One barrier/step.
// T2 swizzle both-sides (pre-swizzled gather source + swizzled read).
// gemm1: 128x256, grid n-chunk-MAJOR (x=n) so co-resident blocks cover few
//        tiles * all n-chunks -> X/W1 working set L2/L3-hot (round-8: tile-major
//        grid re-fetched X, FETCH 94 MB vs ~35 ideal).
// gemm2: 128x128, 49 KB LDS -> 3 blk/CU, 544 blocks/slice (round-8's 272
//        blocks left half the CUs idle).

__global__ __launch_bounds__(512) void gemm1_kernel(
    const short* __restrict__ xbf, const short* __restrict__ w1t,
    const float* __restrict__ b1, const int* __restrict__ offs,
    const int* __restrict__ tile_e, const int* __restrict__ tile_m0,
    const int* __restrict__ list_tok, short* __restrict__ hbuf,
    int h0, int hlen, int t0)
{
    int tb = t0 + (int)blockIdx.y;      // tile index (grid y!)
    if (tb >= offs[17]) return;
    int e = tile_e[tb], m0 = tile_m0[tb];
    int rows = offs[e + 1] - m0; if (rows > GBM) rows = GBM;
    int n0 = blockIdx.x * GBN;          // n-chunk (grid x: fastest-varying)
    int tid = threadIdx.x, l = tid & 63, w = tid >> 6;

    __shared__ __align__(16) short As[3][GBM * BK];   // 3 x 8 KiB
    __shared__ __align__(16) short Bs[3][GBN * BK];   // 3 x 16 KiB
    __shared__ int ts[GBM];
    if (tid < GBM) ts[tid] = list_tok[m0 + (tid < rows ? tid : rows - 1)];
    __syncthreads();

    int arow = w * 16 + (l >> 2);
    int aslot = (l & 3) ^ ((arow >> 1) & 3);
    const short* gA = xbf + (size_t)ts[arow] * DDIM + aslot * 8;
    int brow0 = (w * 2 + 0) * 16 + (l >> 2);
    int brow1 = (w * 2 + 1) * 16 + (l >> 2);
    int bs0 = (l & 3) ^ ((brow0 >> 1) & 3);
    int bs1 = (l & 3) ^ ((brow1 >> 1) & 3);
    const short* gB0 = w1t + ((size_t)e * HDIM + (size_t)(h0 + n0 + brow0)) * DDIM + bs0 * 8;
    const short* gB1 = w1t + ((size_t)e * HDIM + (size_t)(h0 + n0 + brow1)) * DDIM + bs1 * 8;

    int l15 = l & 15, kq = l >> 4;
    int aoff[4], boff[4];
#pragma unroll
    for (int mi = 0; mi < 4; ++mi) {
        int R = (w >> 2) * 64 + mi * 16 + l15;
        aoff[mi] = R * BK + ((kq ^ ((R >> 1) & 3)) * 8);
    }
#pragma unroll
    for (int ni = 0; ni < 4; ++ni) {
        int S = (w & 3) * 64 + ni * 16 + l15;
        boff[ni] = S * BK + ((kq ^ ((S >> 1) & 3)) * 8);
    }

    f32x4 vzero = {0.0f, 0.0f, 0.0f, 0.0f};
    f32x4 acc[4][4];
#pragma unroll
    for (int i = 0; i < 4; ++i)
#pragma unroll
        for (int j = 0; j < 4; ++j) acc[i][j] = vzero;

#define STAGE1(T, B) {                                            \
        gload16(gA  + (T) * BK, &As[B][w * 512]);                 \
        gload16(gB0 + (T) * BK, &Bs[B][(w * 2 + 0) * 512]);       \
        gload16(gB1 + (T) * BK, &Bs[B][(w * 2 + 1) * 512]); }

    const int nt = DDIM / BK;          // 16
    STAGE1(0, 0);
    STAGE1(1, 1);
    int cb = 0, sb = 2;
#pragma unroll 1
    for (int t = 0; t < nt; ++t) {
        if (t < nt - 1) asm volatile("s_waitcnt vmcnt(3)" ::: "memory");
        else            asm volatile("s_waitcnt vmcnt(0)" ::: "memory");
        __builtin_amdgcn_s_barrier();
        __builtin_amdgcn_sched_barrier(0);
        if (t + 2 < nt) STAGE1(t + 2, sb);
        const short* Ab = &As[cb][0];
        const short* Bb = &Bs[cb][0];
        short8 af[4], bv[4];
#pragma unroll
        for (int mi = 0; mi < 4; ++mi) af[mi] = *(const short8*)(Ab + aoff[mi]);
#pragma unroll
        for (int ni = 0; ni < 4; ++ni) bv[ni] = *(const short8*)(Bb + boff[ni]);
        __builtin_amdgcn_s_setprio(1);
#pragma unroll
        for (int mi = 0; mi < 4; ++mi)
#pragma unroll
            for (int ni = 0; ni < 4; ++ni)
                acc[mi][ni] = __builtin_amdgcn_mfma_f32_16x16x32_bf16(
                    af[mi], bv[ni], acc[mi][ni], 0, 0, 0);
        __builtin_amdgcn_s_setprio(0);
        cb = (cb == 2) ? 0 : cb + 1;
        sb = (sb == 2) ? 0 : sb + 1;
    }
#undef STAGE1

    int crow = (w >> 2) * 64 + (kq << 2);
    int ccol = (w & 3) * 64 + l15;
#pragma unroll
    for (int mi = 0; mi < 4; ++mi) {
#pragma unroll
        for (int ni = 0; ni < 4; ++ni) {
            int col = ccol + ni * 16;
            float bias = b1[e * HDIM + h0 + n0 + col];
#pragma unroll
            for (int j = 0; j < 4; ++j) {
                int row = crow + mi * 16 + j;
                if (row < rows) {
                    float v = acc[mi][ni][j] + bias;
                    hbuf[(size_t)(m0 + row) * hlen + (n0 + col)] = f2bf(geluf(v));
                }
            }
        }
    }
}

__global__ __launch_bounds__(512) void gemm2_kernel(
    const short* __restrict__ hbuf, const short* __restrict__ w2t,
    const float* __restrict__ b2, const int* __restrict__ offs,
    const int* __restrict__ tile_e, const int* __restrict__ tile_m0,
    const int* __restrict__ list_tok, const float* __restrict__ list_w,
    short* __restrict__ ybuf, float* __restrict__ out,
    int h0, int hlen, int mode, int t0)
{
    int tb = t0 + (int)blockIdx.y;
    if (tb >= offs[17]) return;
    int e = tile_e[tb], m0 = tile_m0[tb];
    int rows = offs[e + 1] - m0; if (rows > GBM) rows = GBM;
    int n0 = blockIdx.x * GBN2;          // output d coordinate
    int tid = threadIdx.x, l = tid & 63, w = tid >> 6;

    __shared__ __align__(16) short As[3][GBM * BK];    // 3 x 8 KiB
    __shared__ __align__(16) short Bs[3][GBN2 * BK];   // 3 x 8 KiB
    __shared__ int ts[GBM];
    __shared__ float lw[GBM];
    if (tid < GBM) {
        int idx = m0 + (tid < rows ? tid : rows - 1);
        ts[tid] = list_tok[idx];
        lw[tid] = list_w[idx];
    }
    __syncthreads();

    // staging: A rows w*16.., B rows (d) w*16..; 1 gload16 each per wave
    int arow = w * 16 + (l >> 2);
    int aslot = (l & 3) ^ ((arow >> 1) & 3);
    int aslotg = m0 + arow; if (aslotg >= NSLOT) aslotg = NSLOT - 1;
    const short* gA = hbuf + (size_t)aslotg * hlen + aslot * 8;
    int brow = w * 16 + (l >> 2);
    int bslot = (l & 3) ^ ((brow >> 1) & 3);
    const short* gB = w2t + ((size_t)e * DDIM + (size_t)(n0 + brow)) * HDIM + h0 + bslot * 8;

    // wave-grid 2M x 4N: wave-tile 64 x 32
    int l15 = l & 15, kq = l >> 4;
    int aoff[4], boff[2];
#pragma unroll
    for (int mi = 0; mi < 4; ++mi) {
        int R = (w >> 2) * 64 + mi * 16 + l15;
        aoff[mi] = R * BK + ((kq ^ ((R >> 1) & 3)) * 8);
    }
#pragma unroll
    for (int ni = 0; ni < 2; ++ni) {
        int S = (w & 3) * 32 + ni * 16 + l15;
        boff[ni] = S * BK + ((kq ^ ((S >> 1) & 3)) * 8);
    }

    f32x4 vzero = {0.0f, 0.0f, 0.0f, 0.0f};
    f32x4 acc[4][2];
#pragma unroll
    for (int i = 0; i < 4; ++i)
#pragma unroll
        for (int j = 0; j < 2; ++j) acc[i][j] = vzero;

#define STAGE2(T, B) {                                            \
        gload16(gA + (T) * BK, &As[B][w * 512]);                  \
        gload16(gB + (T) * BK, &Bs[B][w * 512]); }

    const int nt = hlen / BK;          // 64 at hlen=2048
    STAGE2(0, 0);
    STAGE2(1, 1);
    int cb = 0, sb = 2;
#pragma unroll 1
    for (int t = 0; t < nt; ++t) {
        if (t < nt - 1) asm volatile("s_waitcnt vmcnt(2)" ::: "memory");
        else            asm volatile("s_waitcnt vmcnt(0)" ::: "memory");
        __builtin_amdgcn_s_barrier();
        __builtin_amdgcn_sched_barrier(0);
        if (t + 2 < nt) STAGE2(t + 2, sb);
        const short* Ab = &As[cb][0];
        const short* Bb = &Bs[cb][0];
        short8 af[4], bv[2];
#pragma unroll
        for (int mi = 0; mi < 4; ++mi) af[mi] = *(const short8*)(Ab + aoff[mi]);
#pragma unroll
        for (int ni = 0; ni < 2; ++ni) bv[ni] = *(const short8*)(Bb + boff[ni]);
        __builtin_amdgcn_s_setprio(1);
#pragma unroll
        for (int mi = 0; mi < 4; ++mi)
#pragma unroll
            for (int ni = 0; ni < 2; ++ni)
                acc[mi][ni] = __builtin_amdgcn_mfma_f32_16x16x32_bf16(
                    af[mi], bv[ni], acc[mi][ni], 0, 0, 0);
        __builtin_amdgcn_s_setprio(0);
        cb = (cb == 2) ? 0 : cb + 1;
        sb = (sb == 2) ? 0 : sb + 1;
    }
#undef STAGE2

    int crow = (w >> 2) * 64 + (kq << 2);
    int ccol = (w & 3) * 32 + l15;
#pragma unroll
    for (int mi = 0; mi < 4; ++mi) {
#pragma unroll
        for (int ni = 0; ni < 2; ++ni) {
            int col = ccol + ni * 16;
            float bias = (h0 == 0) ? b2[e * DDIM + n0 + col] : 0.0f;
#pragma unroll
            for (int j = 0; j < 4; ++j) {
                int row = crow + mi * 16 + j;
                if (row < rows) {
                    float v = acc[mi][ni][j] + bias;
                    if (mode == 0)   // full-K path: single bf16 write
                        ybuf[(size_t)(m0 + row) * DDIM + n0 + col] = f2bf(v);
                    else
                        atomicAdd(&out[(size_t)ts[row] * DDIM + n0 + col], lw[row] * v);
                }
            }
        }
    }
}

// out[t] = w0*ybuf[pos0] + w1*ybuf[pos1]  (ybuf bf16, 8 cols/thread)
__global__ __launch_bounds__(256) void combine_kernel(
    const short* __restrict__ ybuf, const int* __restrict__ pos_tk,
    const float* __restrict__ tok_w, float* __restrict__ out)
{
    int i = blockIdx.x * 256 + threadIdx.x;   // over T_TOK * 64 units
    int t = i >> 6, c = (i & 63) * 8;
    float w0 = tok_w[2 * t], w1 = tok_w[2 * t + 1];
    int p0 = pos_tk[2 * t], p1 = pos_tk[2 * t + 1];
    short8 a = *(const short8*)(ybuf + (size_t)p0 * DDIM + c);
    short8 b = *(const short8*)(ybuf + (size_t)p1 * DDIM + c);
    float4 o0, o1;
    float* op = (float*)&o0;
#pragma unroll
    for (int j = 0; j < 4; ++j) op[j] = w0 * bf2f(a[j]) + w1 * bf2f(b[j]);
    float* op1 = (float*)&o1;
#pragma unroll
    for (int j = 0; j < 4; ++j) op1[j] = w0 * bf2f(a[4 + j]) + w1 * bf2f(b[4 + j]);
    float4* ob = (float4*)(out + (size_t)t * DDIM + c);
    ob[0] = o0;
    ob[1] = o1;
}

// ---------------- launch ----------------

extern "C" void kernel_launch(void* const* d_in, const int* in_sizes, int n_in,
                              void* d_out, int out_size, void* d_ws, size_t ws_size,
                              hipStream_t stream)
{
    const float* x  = (const float*)d_in[0];
    const float* wg = (const float*)d_in[1];
    const float* bg = (const float*)d_in[2];
    const float* w1 = (const float*)d_in[3];
    const float* b1 = (const float*)d_in[4];
    const float* w2 = (const float*)d_in[5];
    const float* b2 = (const float*)d_in[6];
    float* out = (float*)d_out;

    char* p = (char*)d_ws;
    int* offs     = (int*)(p + 128);            // 32 ints
    int* tile_e   = (int*)(p + 256);            // 512 ints
    int* tile_m0  = (int*)(p + 2304);           // 512 ints
    int* bhist    = (int*)(p + 8192);           // 8 KiB
    int* bbase    = (int*)(p + 16384);          // 8 KiB
    int* tok_e    = (int*)(p + 32768);          // 128 KiB
    float* tok_w  = (float*)(p + 32768 + 131072);
    int* list_tok = (int*)(p + 32768 + 262144);
    float* list_w = (float*)(p + 32768 + 393216);
    int* pos_tk   = (int*)(p + 32768 + 524288);
    short* xbf    = (short*)(p + 32768 + 655360);             // 16 MiB
    short* w1t    = xbf + (size_t)T_TOK * DDIM;               // 32 MiB
    short* w2t    = w1t + (size_t)NEXP * DDIM * HDIM;         // 32 MiB
    char* after   = (char*)(w2t + (size_t)NEXP * DDIM * HDIM);
    size_t fixed  = (size_t)(after - p);

    // mode 0: full-K gemm2 + bf16 ybuf + combine (needs hbuf 134 MB + ybuf 33.5 MB)
    // mode 1 fallback: h-chunked gemm2 with atomic out accumulate.
    int mode, hlen = HDIM;
    if (fixed + (size_t)NSLOT * DDIM * 2 + (size_t)NSLOT * HDIM * 2 <= ws_size) {
        mode = 0;
    } else {
        mode = 1;
        hlen = 0;
        for (int hl = HDIM; hl >= 128; hl >>= 1)
            if (fixed + (size_t)NSLOT * hl * 2 <= ws_size) { hlen = hl; break; }
    }
    short* ybuf = (short*)after;
    short* hbuf = (mode == 0) ? (short*)(after + (size_t)NSLOT * DDIM * 2) : (short*)after;

    if (!hlen) { hipMemsetAsync(d_out, 0, (size_t)out_size * sizeof(float), stream); return; }
    if (mode == 1) hipMemsetAsync(d_out, 0, (size_t)out_size * sizeof(float), stream);

    gate_kernel<<<T_TOK / 4, 256, 0, stream>>>(x, wg, bg, tok_e, tok_w);
    hist_kernel<<<NHB, 256, 0, stream>>>(tok_e, bhist);
    scan_kernel<<<1, 64, 0, stream>>>(bhist, offs, bbase, tile_e, tile_m0);
    scatter_kernel<<<NHB, 256, 0, stream>>>(tok_e, tok_w, bbase, list_tok, list_w, pos_tk);
    cvt_bf16_kernel<<<2048, 256, 0, stream>>>(x, xbf, T_TOK * DDIM / 4);
    wtrans_kernel<<<dim3(HDIM / 32, DDIM / 32, NEXP), 256, 0, stream>>>(w1, w1t, DDIM, HDIM);
    wtrans_kernel<<<dim3(DDIM / 32, HDIM / 32, NEXP), 256, 0, stream>>>(w2, w2t, HDIM, DDIM);

    // m-tile slices: gemm2(slice) consumes hbuf(slice) while it is L3-hot.
    // grid.x = n-chunk (fastest) so co-resident blocks share X / W panels.
    for (int h0 = 0; h0 < HDIM; h0 += hlen) {
        for (int t0 = 0; t0 < MAXTILE; t0 += TSLICE) {
            int tc = MAXTILE - t0; if (tc > TSLICE) tc = TSLICE;
            gemm1_kernel<<<dim3(hlen / GBN, tc), 512, 0, stream>>>(
                xbf, w1t, b1, offs, tile_e, tile_m0, list_tok, hbuf, h0, hlen, t0);
            gemm2_kernel<<<dim3(DDIM / GBN2, tc), 512, 0, stream>>>(
                hbuf, w2t, b2, offs, tile_e, tile_m0, list_tok, list_w,
                ybuf, out, h0, hlen, mode, t0);
        }
    }
    if (mode == 0)
        combine_kernel<<<T_TOK * 64 / 256, 256, 0, stream>>>(ybuf, pos_tk, tok_w, out);
}